// Round 3
// baseline (976.605 us; speedup 1.0000x reference)
//
#include <hip/hip_runtime.h>
#include <hip/hip_bf16.h>
#include <stdint.h>

typedef float f32x4 __attribute__((ext_vector_type(4)));
typedef float f32x16 __attribute__((ext_vector_type(16)));
typedef __bf16 bf16x8 __attribute__((ext_vector_type(8)));
typedef unsigned short ushortx8 __attribute__((ext_vector_type(8)));
typedef int i32x4 __attribute__((ext_vector_type(4)));

// ---------------- fp32/i32 -> bf16 conversion ----------------
__device__ __forceinline__ unsigned short f2bf(float f) {
    unsigned u = __builtin_bit_cast(unsigned, f);
    u += 0x7FFFu + ((u >> 16) & 1u);
    return (unsigned short)(u >> 16);
}

__global__ __launch_bounds__(256) void cvt_f32_bf16_kernel(
        const float* __restrict__ in, unsigned short* __restrict__ out, long n) {
    long base = ((long)blockIdx.x * 256 + threadIdx.x) * 8;
    long stride = (long)gridDim.x * 256 * 8;
    for (long i = base; i < n; i += stride) {
        f32x4 v0 = *(const f32x4*)(in + i);
        f32x4 v1 = *(const f32x4*)(in + i + 4);
        ushortx8 o;
        o[0] = f2bf(v0[0]); o[1] = f2bf(v0[1]); o[2] = f2bf(v0[2]); o[3] = f2bf(v0[3]);
        o[4] = f2bf(v1[0]); o[5] = f2bf(v1[1]); o[6] = f2bf(v1[2]); o[7] = f2bf(v1[3]);
        *(ushortx8*)(out + i) = o;
    }
}

__global__ __launch_bounds__(256) void cvt_i32_bf16_kernel(
        const int* __restrict__ in, unsigned short* __restrict__ out, long n) {
    long base = ((long)blockIdx.x * 256 + threadIdx.x) * 8;
    long stride = (long)gridDim.x * 256 * 8;
    for (long i = base; i < n; i += stride) {
        i32x4 v0 = *(const i32x4*)(in + i);
        i32x4 v1 = *(const i32x4*)(in + i + 4);
        ushortx8 o;
        o[0] = f2bf((float)v0[0]); o[1] = f2bf((float)v0[1]);
        o[2] = f2bf((float)v0[2]); o[3] = f2bf((float)v0[3]);
        o[4] = f2bf((float)v1[0]); o[5] = f2bf((float)v1[1]);
        o[6] = f2bf((float)v1[2]); o[7] = f2bf((float)v1[3]);
        *(ushortx8*)(out + i) = o;
    }
}

// ---------------- async global -> LDS (16B/lane, wave-uniform LDS base) ----------------
__device__ __forceinline__ void gload_lds16(const void* g, void* l) {
    __builtin_amdgcn_global_load_lds(
        (const __attribute__((address_space(1))) unsigned int*)g,
        (__attribute__((address_space(3))) unsigned int*)l,
        16, 0, 0);
}

// =====================================================================
// 256x256 8-phase bf16 GEMM (m201 schedule, 32x32x16 MFMA),
// C = A[MxK] * W[NxK]^T * s + b.  512 thr = 8 waves (2M x 4N).
// LDS 128 KiB: region(buf, op, half) = buf*32768 + op*16384 + half*8192 elems,
// each region = 128 rows x 64 cols bf16, row-major 128 B rows,
// XOR-swizzled: LDS[row][cb] holds global colbyte cb ^ ((row&7)<<4).
// =====================================================================

// stage one half-tile (128 rows x 64 cols): 2 issues x (512 lanes x 16 B)
__device__ __forceinline__ void stage_half(const unsigned short* __restrict__ G,
        long grow0, int K, int kcol0, unsigned short* lds_region, int tid) {
    const int r   = tid >> 3;        // 0..63 row within 64-row issue chunk
    const int c8  = tid & 7;         // 16B slot within row
    const int wid = tid >> 6;
#pragma unroll
    for (int j = 0; j < 2; ++j) {
        const int lrow = j * 64 + r;
        const int gcol = kcol0 + ((c8 ^ (lrow & 7)) << 3);   // pre-swizzled source
        gload_lds16(G + (grow0 + lrow) * (long)K + gcol,
                    lds_region + j * 4096 + wid * 512);      // HW adds lane*16B
    }
}

// A fragments for 32x32x16: lane holds row (lane&31), k = (lane>>5)*8 .. +8
template<int BUF, int MH>
__device__ __forceinline__ void readA(const unsigned short* smem, bf16x8 (&fa)[2][4],
                                      int wr, int lane) {
    const unsigned short* rg = smem + BUF * 32768 + MH * 8192;
    const int l31 = lane & 31, kh = lane >> 5;
#pragma unroll
    for (int ml = 0; ml < 2; ++ml) {
        const int lrow = wr * 64 + ml * 32 + l31;
#pragma unroll
        for (int ks = 0; ks < 4; ++ks) {
            const int cb = (ks * 32 + kh * 16) ^ ((lrow & 7) << 4);
            fa[ml][ks] = *(const bf16x8*)(rg + lrow * 64 + (cb >> 1));
        }
    }
}

template<int BUF, int NH>
__device__ __forceinline__ void readB(const unsigned short* smem, bf16x8 (&fb)[4],
                                      int wc, int lane) {
    const unsigned short* rg = smem + BUF * 32768 + 16384 + NH * 8192;
    const int l31 = lane & 31, kh = lane >> 5;
    const int lrow = wc * 32 + l31;
#pragma unroll
    for (int ks = 0; ks < 4; ++ks) {
        const int cb = (ks * 32 + kh * 16) ^ ((lrow & 7) << 4);
        fb[ks] = *(const bf16x8*)(rg + lrow * 64 + (cb >> 1));
    }
}

template<int MH, int NH>
__device__ __forceinline__ void mfmas(f32x16 (&acc)[4][2],
                                      const bf16x8 (&fa)[2][4], const bf16x8 (&fb)[4]) {
#pragma unroll
    for (int ml = 0; ml < 2; ++ml)
#pragma unroll
        for (int ks = 0; ks < 4; ++ks)
            acc[MH * 2 + ml][NH] = __builtin_amdgcn_mfma_f32_32x32x16_bf16(
                fa[ml][ks], fb[ks], acc[MH * 2 + ml][NH], 0, 0, 0);
}

#define SYNC_PRE()  { __builtin_amdgcn_s_barrier();                              \
                      asm volatile("s_waitcnt lgkmcnt(0)" ::: "memory");         \
                      __builtin_amdgcn_sched_barrier(0);                         \
                      __builtin_amdgcn_s_setprio(1); }
#define POST()      { __builtin_amdgcn_s_setprio(0); __builtin_amdgcn_s_barrier(); }
#define POST_V6()   { __builtin_amdgcn_s_setprio(0);                             \
                      asm volatile("s_waitcnt vmcnt(6)" ::: "memory");           \
                      __builtin_amdgcn_s_barrier(); }
#define POST_V0()   { __builtin_amdgcn_s_setprio(0);                             \
                      asm volatile("s_waitcnt vmcnt(0)" ::: "memory");           \
                      __builtin_amdgcn_s_barrier(); }
#define LG8()       { asm volatile("s_waitcnt lgkmcnt(8)" ::: "memory"); }

__global__ __launch_bounds__(512, 1) void gemm_bf16_8phase(
        const unsigned short* __restrict__ A,   // [M][K] bf16 bits
        const unsigned short* __restrict__ W,   // [N][K] bf16 bits
        const float* __restrict__ scales,
        const float* __restrict__ bias,
        float* __restrict__ C,                  // [M][N]
        int M, int N, int K) {
    extern __shared__ unsigned short smem[];    // 65536 elems = 128 KiB

    const int tid  = threadIdx.x;
    const int wid  = tid >> 6;
    const int lane = tid & 63;
    const int wr = wid >> 2;     // 0..1
    const int wc = wid & 3;      // 0..3

    const int nwg = gridDim.x;
    const int bid = blockIdx.x;
    const int swz = ((nwg & 7) == 0) ? ((bid & 7) * (nwg >> 3) + (bid >> 3)) : bid;
    const int tiles_n = N >> 8;
    const int tm = swz / tiles_n;
    const int tn = swz % tiles_n;
    const long arow = (long)tm * 256;
    const long brow = (long)tn * 256;

    f32x16 acc[4][2] = {};
    bf16x8 fa[2][4], fb0[4], fb1[4];

    const int NT = K >> 6;       // K-tiles of 64; NT even, >= 4

#define STA(kt, h) stage_half(A, arow + (h) * 128, K, (kt) * 64, \
                              smem + ((kt) & 1) * 32768 + (h) * 8192, tid)
#define STB(kt, h) stage_half(W, brow + (h) * 128, K, (kt) * 64, \
                              smem + ((kt) & 1) * 32768 + 16384 + (h) * 8192, tid)

    // ---- prologue: 7 half-tile stages (tile0 full + tile1 minus A.h1)
    STA(0, 0); STB(0, 0); STA(0, 1); STB(0, 1);
    STA(1, 0); STB(1, 0); STB(1, 1);
    asm volatile("s_waitcnt vmcnt(6)" ::: "memory");   // tile0's 4 stages landed
    __builtin_amdgcn_s_barrier();

    // ---- main loop: iteration consumes tiles (2i)->buf0, (2i+1)->buf1
    for (int i = 0; i < (NT >> 1) - 1; ++i) {
        const int b = 2 * i + 1, c = 2 * i + 2, d = 2 * i + 3;
        // ph1 (mh0,nh0 of buf0)
        readA<0, 0>(smem, fa, wr, lane); readB<0, 0>(smem, fb0, wc, lane); STA(b, 1);
        LG8(); SYNC_PRE(); mfmas<0, 0>(acc, fa, fb0); POST();
        // ph2 (mh0,nh1)
        readB<0, 1>(smem, fb1, wc, lane); STA(c, 0);
        SYNC_PRE(); mfmas<0, 1>(acc, fa, fb1); POST();
        // ph3 (mh1,nh0)
        readA<0, 1>(smem, fa, wr, lane); STB(c, 0);
        SYNC_PRE(); mfmas<1, 0>(acc, fa, fb0); POST();
        // ph4 (mh1,nh1) + fence
        STB(c, 1);
        SYNC_PRE(); mfmas<1, 1>(acc, fa, fb1); POST_V6();
        // ph5 (mh0,nh0 of buf1)
        readA<1, 0>(smem, fa, wr, lane); readB<1, 0>(smem, fb0, wc, lane); STA(c, 1);
        LG8(); SYNC_PRE(); mfmas<0, 0>(acc, fa, fb0); POST();
        // ph6
        readB<1, 1>(smem, fb1, wc, lane); STA(d, 0);
        SYNC_PRE(); mfmas<0, 1>(acc, fa, fb1); POST();
        // ph7
        readA<1, 1>(smem, fa, wr, lane); STB(d, 0);
        SYNC_PRE(); mfmas<1, 0>(acc, fa, fb0); POST();
        // ph8 + fence
        STB(d, 1);
        SYNC_PRE(); mfmas<1, 1>(acc, fa, fb1); POST_V6();
    }

    // ---- epilogue iteration: tiles NT-2 (buf0), NT-1 (buf1); no prefetch
    readA<0, 0>(smem, fa, wr, lane); readB<0, 0>(smem, fb0, wc, lane); STA(NT - 1, 1);
    LG8(); SYNC_PRE(); mfmas<0, 0>(acc, fa, fb0); POST();
    readB<0, 1>(smem, fb1, wc, lane);
    SYNC_PRE(); mfmas<0, 1>(acc, fa, fb1); POST();
    readA<0, 1>(smem, fa, wr, lane);
    SYNC_PRE(); mfmas<1, 0>(acc, fa, fb0); POST();
    SYNC_PRE(); mfmas<1, 1>(acc, fa, fb1); POST_V0();   // drain: tile NT-1 fully landed
    readA<1, 0>(smem, fa, wr, lane); readB<1, 0>(smem, fb0, wc, lane);
    SYNC_PRE(); mfmas<0, 0>(acc, fa, fb0); POST();
    readB<1, 1>(smem, fb1, wc, lane);
    SYNC_PRE(); mfmas<0, 1>(acc, fa, fb1); POST();
    readA<1, 1>(smem, fa, wr, lane);
    SYNC_PRE(); mfmas<1, 0>(acc, fa, fb0); POST();
    SYNC_PRE(); mfmas<1, 1>(acc, fa, fb1);
    __builtin_amdgcn_s_setprio(0);

#undef STA
#undef STB

    // ---- C write: out = acc * scales[col] + bias[col]
    // 32x32 C/D layout: col = lane&31, row = (reg&3) + 8*(reg>>2) + 4*(lane>>5)
#pragma unroll
    for (int nf = 0; nf < 2; ++nf) {
        const int col = tn * 256 + nf * 128 + wc * 32 + (lane & 31);
        const float s = scales[col];
        const float bb = bias[col];
#pragma unroll
        for (int mh = 0; mh < 2; ++mh)
#pragma unroll
            for (int ml = 0; ml < 2; ++ml) {
                const long row0 = arow + mh * 128 + wr * 64 + ml * 32 + ((lane >> 5) << 2);
#pragma unroll
                for (int r = 0; r < 16; ++r) {
                    const long row = row0 + (r & 3) + ((r >> 2) << 3);
                    __builtin_nontemporal_store(acc[mh * 2 + ml][nf][r] * s + bb,
                                                &C[row * (long)N + col]);
                }
            }
    }
}

// =====================================================================
// fallback #1: verified 128^2 m97-structure kernel (round-1)
// =====================================================================
__global__ __launch_bounds__(256, 3) void gemm_bf16_128(
        const unsigned short* __restrict__ A, const unsigned short* __restrict__ W,
        const float* __restrict__ scales, const float* __restrict__ bias,
        float* __restrict__ C, int M, int N, int K) {
    __shared__ unsigned short As[128 * 32];
    __shared__ unsigned short Ws[128 * 32];
    const int tid = threadIdx.x, wave = tid >> 6, lane = tid & 63;
    const int nwg = gridDim.x;
    int bid = blockIdx.x;
    int swz = ((nwg & 7) == 0) ? ((bid & 7) * (nwg >> 3) + (bid >> 3)) : bid;
    const int tiles_n = N / 128;
    const int tm = swz / tiles_n, tn = swz % tiles_n;
    const int wr = wave >> 1, wc = wave & 1;
    const int fr = lane & 15, fq = lane >> 4;
    const int srow = lane >> 2, scol = (lane & 3) * 8;
    const long rowA0 = (long)tm * 128, rowW0 = (long)tn * 128;
    f32x4 acc[4][4] = {};
    const int nk = K / 32;
    for (int kt = 0; kt < nk; ++kt) {
        __syncthreads();
        const int k0 = kt * 32;
#pragma unroll
        for (int i = 0; i < 2; ++i) {
            const int r = i * 64 + wave * 16 + srow;
            const size_t loff = (size_t)(i * 2048 + wave * 512);
            gload_lds16(A + (rowA0 + r) * (long)K + k0 + scol, (void*)(As + loff));
            gload_lds16(W + (rowW0 + r) * (long)K + k0 + scol, (void*)(Ws + loff));
        }
        __syncthreads();
        bf16x8 af[4], wf[4];
#pragma unroll
        for (int m = 0; m < 4; ++m)
            af[m] = *(const bf16x8*)(As + (wr * 64 + m * 16 + fr) * 32 + fq * 8);
#pragma unroll
        for (int n = 0; n < 4; ++n)
            wf[n] = *(const bf16x8*)(Ws + (wc * 64 + n * 16 + fr) * 32 + fq * 8);
#pragma unroll
        for (int m = 0; m < 4; ++m)
#pragma unroll
            for (int n = 0; n < 4; ++n)
                acc[m][n] = __builtin_amdgcn_mfma_f32_16x16x32_bf16(af[m], wf[n], acc[m][n], 0, 0, 0);
    }
#pragma unroll
    for (int n = 0; n < 4; ++n) {
        const int col = tn * 128 + wc * 64 + n * 16 + fr;
        const float s = scales[col], b = bias[col];
#pragma unroll
        for (int m = 0; m < 4; ++m) {
            const int row0 = tm * 128 + wr * 64 + m * 16 + fq * 4;
#pragma unroll
            for (int j = 0; j < 4; ++j)
                C[(long)(row0 + j) * N + col] = acc[m][n][j] * s + b;
        }
    }
}

// fallback #2: fp32 (no ws / odd shapes)
__global__ __launch_bounds__(256) void gemm_fallback_kernel(
        const float* __restrict__ A, const int* __restrict__ W,
        const float* __restrict__ scales, const float* __restrict__ bias,
        float* __restrict__ C, int M, int N, int K) {
    __shared__ float As[64][16];
    __shared__ float Ws[64][16];
    const int tiles_n = N / 64;
    const int tm = blockIdx.x / tiles_n, tn = blockIdx.x % tiles_n;
    const int tid = threadIdx.x, tx = tid & 15, ty = tid >> 4;
    float acc[4][4] = {};
    for (int k0 = 0; k0 < K; k0 += 16) {
        __syncthreads();
#pragma unroll
        for (int i = 0; i < 4; ++i) {
            const int idx = tid + i * 256;
            const int r = idx >> 4, c = idx & 15;
            As[r][c] = A[(long)(tm * 64 + r) * K + k0 + c];
            Ws[r][c] = (float)W[(long)(tn * 64 + r) * K + k0 + c];
        }
        __syncthreads();
#pragma unroll
        for (int kk = 0; kk < 16; ++kk) {
            float a[4], w[4];
#pragma unroll
            for (int r = 0; r < 4; ++r) a[r] = As[ty * 4 + r][kk];
#pragma unroll
            for (int c = 0; c < 4; ++c) w[c] = Ws[tx * 4 + c][kk];
#pragma unroll
            for (int r = 0; r < 4; ++r)
#pragma unroll
                for (int c = 0; c < 4; ++c) acc[r][c] += a[r] * w[c];
        }
    }
#pragma unroll
    for (int r = 0; r < 4; ++r)
#pragma unroll
        for (int c = 0; c < 4; ++c) {
            const int col = tn * 64 + tx * 4 + c;
            C[(long)(tm * 64 + ty * 4 + r) * N + col] = acc[r][c] * scales[col] + bias[col];
        }
}

extern "C" void kernel_launch(void* const* d_in, const int* in_sizes, int n_in,
                              void* d_out, int out_size, void* d_ws, size_t ws_size,
                              hipStream_t stream) {
    const float* A32    = (const float*)d_in[0];
    const int*   Wq     = (const int*)d_in[1];
    const float* scales = (const float*)d_in[2];
    const float* bias   = (const float*)d_in[3];
    float* C = (float*)d_out;

    const long aElems = in_sizes[0];
    const long wElems = in_sizes[1];
    const int  N = in_sizes[2];
    const int  K = (int)(wElems / N);
    const int  M = (int)(aElems / K);

    const size_t need = (size_t)(aElems + wElems) * 2;
    const bool div256 = (M % 256 == 0) && (N % 256 == 0) && (K % 256 == 0);
    const bool div128 = (M % 128 == 0) && (N % 128 == 0) && (K % 32 == 0);

    if (ws_size >= need && (div256 || div128)) {
        unsigned short* Abf = (unsigned short*)d_ws;
        unsigned short* Wbf = Abf + aElems;
        cvt_f32_bf16_kernel<<<2048, 256, 0, stream>>>(A32, Abf, aElems);
        cvt_i32_bf16_kernel<<<2048, 256, 0, stream>>>(Wq, Wbf, wElems);
        if (div256) {
            const int nwg = (M / 256) * (N / 256);
            gemm_bf16_8phase<<<nwg, 512, 131072, stream>>>(Abf, Wbf, scales, bias, C, M, N, K);
        } else {
            const int nwg = (M / 128) * (N / 128);
            gemm_bf16_128<<<nwg, 256, 0, stream>>>(Abf, Wbf, scales, bias, C, M, N, K);
        }
    } else {
        const int nwg = (M / 64) * (N / 64);
        gemm_fallback_kernel<<<nwg, 256, 0, stream>>>(A32, Wq, scales, bias, C, M, N, K);
    }
}

// Round 4
// 490.822 us; speedup vs baseline: 1.9897x; 1.9897x over previous
//
#include <hip/hip_runtime.h>
#include <hip/hip_bf16.h>
#include <stdint.h>

typedef float f32x4 __attribute__((ext_vector_type(4)));
typedef int i32x4 __attribute__((ext_vector_type(4)));

// ---------------- async global -> LDS (16B/lane, wave-uniform LDS base) ----------------
__device__ __forceinline__ void gload_lds16(const void* g, void* l) {
    __builtin_amdgcn_global_load_lds(
        (const __attribute__((address_space(1))) unsigned int*)g,
        (__attribute__((address_space(3))) unsigned int*)l,
        16, 0, 0);
}

// ---------------- per-row activation quantization: f32 -> i8, qrow = amax/127 ----------------
__global__ __launch_bounds__(256) void quant_rows_kernel(
        const float* __restrict__ A, signed char* __restrict__ Aq,
        float* __restrict__ qrow, int K) {
    const long row = blockIdx.x;
    const float* a = A + row * (long)K;
    signed char* o = Aq + row * (long)K;
    const int tid = threadIdx.x;
    const int nch = K >> 2;                       // f32x4 chunks per row
    float amax = 0.f;
    for (int c = tid; c < nch; c += 256) {
        f32x4 v = ((const f32x4*)a)[c];
        amax = fmaxf(amax, fmaxf(fmaxf(fabsf(v[0]), fabsf(v[1])),
                                 fmaxf(fabsf(v[2]), fabsf(v[3]))));
    }
#pragma unroll
    for (int off = 32; off; off >>= 1)
        amax = fmaxf(amax, __shfl_xor(amax, off, 64));
    __shared__ float red[4];
    if ((tid & 63) == 0) red[tid >> 6] = amax;
    __syncthreads();
    amax = fmaxf(fmaxf(red[0], red[1]), fmaxf(red[2], red[3]));
    const float s = amax > 0.f ? 127.f / amax : 0.f;
    if (tid == 0) qrow[row] = amax > 0.f ? amax / 127.f : 0.f;
    for (int c = tid; c < nch; c += 256) {       // second sweep: row is L1/L2-hot
        f32x4 v = ((const f32x4*)a)[c];
        int r = 0;
#pragma unroll
        for (int i = 0; i < 4; ++i) {
            int q = (int)__builtin_rintf(v[i] * s);
            r |= (q & 0xff) << (8 * i);
        }
        ((int*)o)[c] = r;
    }
}

// ---------------- weight conversion: i32 (int8-range) -> i8, exact ----------------
__global__ __launch_bounds__(256) void cvt_i32_i8_kernel(
        const int* __restrict__ in, signed char* __restrict__ out, long n) {
    long base = ((long)blockIdx.x * 256 + threadIdx.x) * 16;
    long stride = (long)gridDim.x * 256 * 16;
    for (long i = base; i < n; i += stride) {
        i32x4 pk;
#pragma unroll
        for (int c = 0; c < 4; ++c) {
            i32x4 v = *(const i32x4*)(in + i + c * 4);
            pk[c] = (v[0] & 0xff) | ((v[1] & 0xff) << 8) |
                    ((v[2] & 0xff) << 16) | ((v[3] & 0xff) << 24);
        }
        *(i32x4*)(out + i) = pk;
    }
}

// =====================================================================
// 256x256 8-phase i8 GEMM (m201 schedule, mfma_i32_16x16x64_i8),
// C = (Aq[MxK]*qrow[row]) * (Wq[NxK])^T * s[col] + b[col].
// 512 thr = 8 waves (2M x 4N).  LDS 64 KiB:
// region(buf,op,half) = buf*32768 + op*16384 + half*8192 BYTES,
// each region = 128 rows x 64 cols i8, row-major 64 B rows,
// swizzle: LDS[row][slot16B] holds global k-chunk slot ^ ((row>>1)&3).
// =====================================================================

// stage one half-tile (128 rows x 64 cols i8): ONE issue of 512 lanes x 16 B
__device__ __forceinline__ void stage_half(const signed char* __restrict__ G,
        long grow0, int K, int kcol0, signed char* lds_region, int tid) {
    const int row  = tid >> 2;                       // 0..127
    const int slot = tid & 3;                        // 16B slot within 64B row
    const int gcol = kcol0 + ((slot ^ ((row >> 1) & 3)) << 4);  // pre-swizzled source
    const int wid  = tid >> 6;
    gload_lds16(G + (grow0 + row) * (long)K + gcol,
                lds_region + wid * 1024);            // HW adds lane*16B
}

// A fragments 16x16x64: lane holds row (lane&15), k = (lane>>4)*16 + 0..15 (one b128)
template<int BUF, int MH>
__device__ __forceinline__ void readA(const signed char* smem, i32x4 (&fa)[4],
                                      int wr, int lane) {
    const signed char* rg = smem + BUF * 32768 + MH * 8192;
    const int fr = lane & 15, kg = lane >> 4;
#pragma unroll
    for (int ml = 0; ml < 4; ++ml) {
        const int lrow = wr * 16 + ml * 32 + fr;
        fa[ml] = *(const i32x4*)(rg + lrow * 64 + ((kg ^ ((lrow >> 1) & 3)) << 4));
    }
}

template<int BUF, int NH>
__device__ __forceinline__ void readB(const signed char* smem, i32x4 (&fb)[2],
                                      int wc, int lane) {
    const signed char* rg = smem + BUF * 32768 + 16384 + NH * 8192;
    const int fr = lane & 15, kg = lane >> 4;
#pragma unroll
    for (int nl = 0; nl < 2; ++nl) {
        const int lrow = wc * 16 + nl * 64 + fr;
        fb[nl] = *(const i32x4*)(rg + lrow * 64 + ((kg ^ ((lrow >> 1) & 3)) << 4));
    }
}

template<int MH, int NH>
__device__ __forceinline__ void mfmas(i32x4 (&acc)[8][4],
                                      const i32x4 (&fa)[4], const i32x4 (&fb)[2]) {
#pragma unroll
    for (int ml = 0; ml < 4; ++ml)
#pragma unroll
        for (int nl = 0; nl < 2; ++nl)
            acc[MH * 4 + ml][NH * 2 + nl] = __builtin_amdgcn_mfma_i32_16x16x64_i8(
                fa[ml], fb[nl], acc[MH * 4 + ml][NH * 2 + nl], 0, 0, 0);
}

#define SYNC_PRE()  { __builtin_amdgcn_s_barrier();                              \
                      asm volatile("s_waitcnt lgkmcnt(0)" ::: "memory");         \
                      __builtin_amdgcn_sched_barrier(0);                         \
                      __builtin_amdgcn_s_setprio(1); }
#define POST()      { __builtin_amdgcn_s_setprio(0); __builtin_amdgcn_s_barrier(); }
#define POST_V3()   { __builtin_amdgcn_s_setprio(0);                             \
                      asm volatile("s_waitcnt vmcnt(3)" ::: "memory");           \
                      __builtin_amdgcn_s_barrier(); }
#define POST_V0()   { __builtin_amdgcn_s_setprio(0);                             \
                      asm volatile("s_waitcnt vmcnt(0)" ::: "memory");           \
                      __builtin_amdgcn_s_barrier(); }

__global__ __launch_bounds__(512, 1) void gemm_i8_8phase(
        const signed char* __restrict__ A,      // [M][K] i8
        const signed char* __restrict__ W,      // [N][K] i8
        const float* __restrict__ qrow,         // [M] row dequant scale
        const float* __restrict__ scales,       // [N]
        const float* __restrict__ bias,         // [N]
        float* __restrict__ C,                  // [M][N]
        int M, int N, int K) {
    extern __shared__ signed char smem[];       // 65536 B

    const int tid  = threadIdx.x;
    const int wid  = tid >> 6;
    const int lane = tid & 63;
    const int wr = wid >> 2;     // 0..1
    const int wc = wid & 3;      // 0..3
    const int fr = lane & 15;
    const int fq = lane >> 4;

    const int nwg = gridDim.x;
    const int bid = blockIdx.x;
    const int swz = ((nwg & 7) == 0) ? ((bid & 7) * (nwg >> 3) + (bid >> 3)) : bid;
    const int tiles_n = N >> 8;
    const int tm = swz / tiles_n;
    const int tn = swz % tiles_n;
    const long arow = (long)tm * 256;
    const long brow = (long)tn * 256;

    i32x4 acc[8][4] = {};
    i32x4 fa[4], fb0[2], fb1[2];

    const int NT = K >> 6;       // K-tiles of 64; NT even, >= 4

#define STA(kt, h) stage_half(A, arow + (h) * 128, K, (kt) * 64, \
                              smem + ((kt) & 1) * 32768 + (h) * 8192, tid)
#define STB(kt, h) stage_half(W, brow + (h) * 128, K, (kt) * 64, \
                              smem + ((kt) & 1) * 32768 + 16384 + (h) * 8192, tid)

    // ---- prologue: 7 half-tile stages (tile0 full + tile1 minus A.h1)
    STA(0, 0); STB(0, 0); STA(0, 1); STB(0, 1);
    STA(1, 0); STB(1, 0); STB(1, 1);
    asm volatile("s_waitcnt vmcnt(3)" ::: "memory");   // tile0's 4 stages landed
    __builtin_amdgcn_s_barrier();

    // ---- main loop: iteration consumes tiles (2i)->buf0, (2i+1)->buf1
    for (int i = 0; i < (NT >> 1) - 1; ++i) {
        const int b = 2 * i + 1, c = 2 * i + 2, d = 2 * i + 3;
        // ph1 (mh0,nh0 of buf0)
        readA<0, 0>(smem, fa, wr, lane); readB<0, 0>(smem, fb0, wc, lane); STA(b, 1);
        SYNC_PRE(); mfmas<0, 0>(acc, fa, fb0); POST();
        // ph2 (mh0,nh1)
        readB<0, 1>(smem, fb1, wc, lane); STA(c, 0);
        SYNC_PRE(); mfmas<0, 1>(acc, fa, fb1); POST();
        // ph3 (mh1,nh0)
        readA<0, 1>(smem, fa, wr, lane); STB(c, 0);
        SYNC_PRE(); mfmas<1, 0>(acc, fa, fb0); POST();
        // ph4 (mh1,nh1) + fence: tile b fully landed before ph5 reads buf1
        STB(c, 1);
        SYNC_PRE(); mfmas<1, 1>(acc, fa, fb1); POST_V3();
        // ph5 (mh0,nh0 of buf1)
        readA<1, 0>(smem, fa, wr, lane); readB<1, 0>(smem, fb0, wc, lane); STA(c, 1);
        SYNC_PRE(); mfmas<0, 0>(acc, fa, fb0); POST();
        // ph6
        readB<1, 1>(smem, fb1, wc, lane); STA(d, 0);
        SYNC_PRE(); mfmas<0, 1>(acc, fa, fb1); POST();
        // ph7
        readA<1, 1>(smem, fa, wr, lane); STB(d, 0);
        SYNC_PRE(); mfmas<1, 0>(acc, fa, fb0); POST();
        // ph8 + fence: tile c fully landed before next-iter ph1 reads buf0
        STB(d, 1);
        SYNC_PRE(); mfmas<1, 1>(acc, fa, fb1); POST_V3();
    }

    // ---- epilogue iteration: tiles NT-2 (buf0), NT-1 (buf1); no further prefetch
    readA<0, 0>(smem, fa, wr, lane); readB<0, 0>(smem, fb0, wc, lane); STA(NT - 1, 1);
    SYNC_PRE(); mfmas<0, 0>(acc, fa, fb0); POST();
    readB<0, 1>(smem, fb1, wc, lane);
    SYNC_PRE(); mfmas<0, 1>(acc, fa, fb1); POST();
    readA<0, 1>(smem, fa, wr, lane);
    SYNC_PRE(); mfmas<1, 0>(acc, fa, fb0); POST();
    SYNC_PRE(); mfmas<1, 1>(acc, fa, fb1); POST_V0();   // drain: tile NT-1 fully landed
    readA<1, 0>(smem, fa, wr, lane); readB<1, 0>(smem, fb0, wc, lane);
    SYNC_PRE(); mfmas<0, 0>(acc, fa, fb0); POST();
    readB<1, 1>(smem, fb1, wc, lane);
    SYNC_PRE(); mfmas<0, 1>(acc, fa, fb1); POST();
    readA<1, 1>(smem, fa, wr, lane);
    SYNC_PRE(); mfmas<1, 0>(acc, fa, fb0); POST();
    SYNC_PRE(); mfmas<1, 1>(acc, fa, fb1);
    __builtin_amdgcn_s_setprio(0);

#undef STA
#undef STB

    // ---- dequant row scales: qr[m][j] for this thread's 32 output rows
    float qr[8][4];
#pragma unroll
    for (int mh = 0; mh < 2; ++mh)
#pragma unroll
        for (int ml = 0; ml < 4; ++ml) {
            const long row0 = arow + wr * 16 + mh * 128 + ml * 32 + fq * 4;
#pragma unroll
            for (int j = 0; j < 4; ++j)
                qr[mh * 4 + ml][j] = qrow[row0 + j];
        }

    // ---- C write: out = acc * qrow[row] * scales[col] + bias[col]
    // 16x16 C/D layout: col = lane&15, row = (lane>>4)*4 + reg
#pragma unroll
    for (int n = 0; n < 4; ++n) {
        const int col = tn * 256 + wc * 16 + n * 64 + fr;
        const float s = scales[col];
        const float bb = bias[col];
#pragma unroll
        for (int mh = 0; mh < 2; ++mh)
#pragma unroll
            for (int ml = 0; ml < 4; ++ml) {
                const int m = mh * 4 + ml;
                const long row0 = arow + wr * 16 + mh * 128 + ml * 32 + fq * 4;
#pragma unroll
                for (int j = 0; j < 4; ++j)
                    C[(row0 + j) * (long)N + col] =
                        (float)acc[m][n][j] * (qr[m][j] * s) + bb;
            }
    }
}

// ---------------- fallback: plain fp32 (odd shapes / tiny ws only) ----------------
__global__ __launch_bounds__(256) void gemm_fallback_kernel(
        const float* __restrict__ A, const int* __restrict__ W,
        const float* __restrict__ scales, const float* __restrict__ bias,
        float* __restrict__ C, int M, int N, int K) {
    __shared__ float As[64][16];
    __shared__ float Ws[64][16];
    const int tiles_n = N / 64;
    const int tm = blockIdx.x / tiles_n, tn = blockIdx.x % tiles_n;
    const int tid = threadIdx.x, tx = tid & 15, ty = tid >> 4;
    float acc[4][4] = {};
    for (int k0 = 0; k0 < K; k0 += 16) {
        __syncthreads();
#pragma unroll
        for (int i = 0; i < 4; ++i) {
            const int idx = tid + i * 256;
            const int r = idx >> 4, c = idx & 15;
            As[r][c] = A[(long)(tm * 64 + r) * K + k0 + c];
            Ws[r][c] = (float)W[(long)(tn * 64 + r) * K + k0 + c];
        }
        __syncthreads();
#pragma unroll
        for (int kk = 0; kk < 16; ++kk) {
            float a[4], w[4];
#pragma unroll
            for (int r = 0; r < 4; ++r) a[r] = As[ty * 4 + r][kk];
#pragma unroll
            for (int c = 0; c < 4; ++c) w[c] = Ws[tx * 4 + c][kk];
#pragma unroll
            for (int r = 0; r < 4; ++r)
#pragma unroll
                for (int c = 0; c < 4; ++c) acc[r][c] += a[r] * w[c];
        }
    }
#pragma unroll
    for (int r = 0; r < 4; ++r)
#pragma unroll
        for (int c = 0; c < 4; ++c) {
            const int col = tn * 64 + tx * 4 + c;
            C[(long)(tm * 64 + ty * 4 + r) * N + col] = acc[r][c] * scales[col] + bias[col];
        }
}

extern "C" void kernel_launch(void* const* d_in, const int* in_sizes, int n_in,
                              void* d_out, int out_size, void* d_ws, size_t ws_size,
                              hipStream_t stream) {
    const float* A32    = (const float*)d_in[0];
    const int*   Wq     = (const int*)d_in[1];
    const float* scales = (const float*)d_in[2];
    const float* bias   = (const float*)d_in[3];
    float* C = (float*)d_out;

    const long aElems = in_sizes[0];        // M*K
    const long wElems = in_sizes[1];        // N*K
    const int  N = in_sizes[2];
    const int  K = (int)(wElems / N);
    const int  M = (int)(aElems / K);

    const size_t need = (size_t)aElems + (size_t)wElems + (size_t)M * 4 + 64;
    const bool div256 = (M % 256 == 0) && (N % 256 == 0) && (K % 128 == 0) && (K >= 256);

    if (ws_size >= need && div256) {
        signed char* Aq  = (signed char*)d_ws;
        signed char* Wq8 = Aq + aElems;
        float* qrow = (float*)(Wq8 + wElems);
        quant_rows_kernel<<<M, 256, 0, stream>>>(A32, Aq, qrow, K);
        cvt_i32_i8_kernel<<<2048, 256, 0, stream>>>(Wq, Wq8, wElems);
        const int nwg = (M / 256) * (N / 256);
        gemm_i8_8phase<<<nwg, 512, 65536, stream>>>(Aq, Wq8, qrow, scales, bias, C, M, N, K);
    } else {
        const int nwg = (M / 64) * (N / 64);
        gemm_fallback_kernel<<<nwg, 256, 0, stream>>>(A32, Wq, scales, bias, C, M, N, K);
    }
}

// Round 5
// 464.044 us; speedup vs baseline: 2.1046x; 1.0577x over previous
//
#include <hip/hip_runtime.h>
#include <hip/hip_bf16.h>
#include <stdint.h>

typedef float f32x4 __attribute__((ext_vector_type(4)));
typedef int i32x4 __attribute__((ext_vector_type(4)));

// ---------------- async global -> LDS (16B/lane, wave-uniform LDS base) ----------------
__device__ __forceinline__ void gload_lds16(const void* g, void* l) {
    __builtin_amdgcn_global_load_lds(
        (const __attribute__((address_space(1))) unsigned int*)g,
        (__attribute__((address_space(3))) unsigned int*)l,
        16, 0, 0);
}

// ---------------- per-row activation quantization: f32 -> i8, qrow = amax/127 ----------------
__global__ __launch_bounds__(256) void quant_rows_kernel(
        const float* __restrict__ A, signed char* __restrict__ Aq,
        float* __restrict__ qrow, int K) {
    const long row = blockIdx.x;
    const float* a = A + row * (long)K;
    signed char* o = Aq + row * (long)K;
    const int tid = threadIdx.x;
    const int nch = K >> 2;                       // f32x4 chunks per row
    float amax = 0.f;
    for (int c = tid; c < nch; c += 256) {
        f32x4 v = ((const f32x4*)a)[c];
        amax = fmaxf(amax, fmaxf(fmaxf(fabsf(v[0]), fabsf(v[1])),
                                 fmaxf(fabsf(v[2]), fabsf(v[3]))));
    }
#pragma unroll
    for (int off = 32; off; off >>= 1)
        amax = fmaxf(amax, __shfl_xor(amax, off, 64));
    __shared__ float red[4];
    if ((tid & 63) == 0) red[tid >> 6] = amax;
    __syncthreads();
    amax = fmaxf(fmaxf(red[0], red[1]), fmaxf(red[2], red[3]));
    const float s = amax > 0.f ? 127.f / amax : 0.f;
    if (tid == 0) qrow[row] = amax > 0.f ? amax / 127.f : 0.f;
    for (int c = tid; c < nch; c += 256) {       // second sweep: row is L1/L2-hot
        f32x4 v = ((const f32x4*)a)[c];
        int r = 0;
#pragma unroll
        for (int i = 0; i < 4; ++i) {
            int q = (int)__builtin_rintf(v[i] * s);
            r |= (q & 0xff) << (8 * i);
        }
        ((int*)o)[c] = r;
    }
}

// ---------------- weight conversion: i32 (int8-range) -> i8, exact ----------------
__global__ __launch_bounds__(256) void cvt_i32_i8_kernel(
        const int* __restrict__ in, signed char* __restrict__ out, long n) {
    long base = ((long)blockIdx.x * 256 + threadIdx.x) * 16;
    long stride = (long)gridDim.x * 256 * 16;
    for (long i = base; i < n; i += stride) {
        i32x4 pk;
#pragma unroll
        for (int c = 0; c < 4; ++c) {
            i32x4 v = *(const i32x4*)(in + i + c * 4);
            pk[c] = (v[0] & 0xff) | ((v[1] & 0xff) << 8) |
                    ((v[2] & 0xff) << 16) | ((v[3] & 0xff) << 24);
        }
        *(i32x4*)(out + i) = pk;
    }
}

// =====================================================================
// 256x256 8-phase i8 GEMM, K-tile=128 (round-2 verified geometry in i8),
// mfma_i32_16x16x64_i8.  C = (Aq*qrow[row]) * Wq^T * s[col] + b[col].
// 512 thr = 8 waves (2M x 4N).  LDS 128 KiB:
// region(buf,op,half) = buf*65536 + op*32768 + half*16384 BYTES,
// each region = 128 rows x 128 cols i8, row-major 128-B rows, 8 x 16B slots,
// swizzle: LDS[row][slot] holds global k-chunk slot ^ (row&7)  (st_16x32).
// =====================================================================

// stage one half-tile (128 rows x 128 cols i8): 2 issues x (512 lanes x 16 B)
__device__ __forceinline__ void stage_half(const signed char* __restrict__ G,
        long grow0, int K, int kcol0, signed char* lds_region, int tid) {
    const int r   = tid >> 3;        // 0..63 row within 64-row issue chunk
    const int c8  = tid & 7;         // 16B slot within 128-B row
    const int wid = tid >> 6;
#pragma unroll
    for (int j = 0; j < 2; ++j) {
        const int lrow = j * 64 + r;
        const int gcol = kcol0 + ((c8 ^ (lrow & 7)) << 4);   // pre-swizzled source
        gload_lds16(G + (grow0 + lrow) * (long)K + gcol,
                    lds_region + j * 8192 + wid * 1024);     // HW adds lane*16B
    }
}

// A fragments 16x16x64: lane holds row (lane&15), k = ks*64 + (lane>>4)*16 + 0..15
template<int BUF, int MH>
__device__ __forceinline__ void readA(const signed char* smem, i32x4 (&fa)[4][2],
                                      int wr, int lane) {
    const signed char* rg = smem + BUF * 65536 + MH * 16384;
    const int fr = lane & 15, kg = lane >> 4;
#pragma unroll
    for (int ml = 0; ml < 4; ++ml) {
        const int lrow = wr * 16 + ml * 32 + fr;
#pragma unroll
        for (int ks = 0; ks < 2; ++ks)
            fa[ml][ks] = *(const i32x4*)(rg + lrow * 128 +
                             (((ks * 4 + kg) ^ (lrow & 7)) << 4));
    }
}

template<int BUF, int NH>
__device__ __forceinline__ void readB(const signed char* smem, i32x4 (&fb)[2][2],
                                      int wc, int lane) {
    const signed char* rg = smem + BUF * 65536 + 32768 + NH * 16384;
    const int fr = lane & 15, kg = lane >> 4;
#pragma unroll
    for (int nl = 0; nl < 2; ++nl) {
        const int lrow = wc * 16 + nl * 64 + fr;
#pragma unroll
        for (int ks = 0; ks < 2; ++ks)
            fb[nl][ks] = *(const i32x4*)(rg + lrow * 128 +
                             (((ks * 4 + kg) ^ (lrow & 7)) << 4));
    }
}

template<int MH, int NH>
__device__ __forceinline__ void mfmas(i32x4 (&acc)[8][4],
                                      const i32x4 (&fa)[4][2], const i32x4 (&fb)[2][2]) {
#pragma unroll
    for (int ml = 0; ml < 4; ++ml)
#pragma unroll
        for (int nl = 0; nl < 2; ++nl)
#pragma unroll
            for (int ks = 0; ks < 2; ++ks)
                acc[MH * 4 + ml][NH * 2 + nl] = __builtin_amdgcn_mfma_i32_16x16x64_i8(
                    fa[ml][ks], fb[nl][ks], acc[MH * 4 + ml][NH * 2 + nl], 0, 0, 0);
}

#define SYNC_PRE()  { __builtin_amdgcn_s_barrier();                              \
                      asm volatile("s_waitcnt lgkmcnt(0)" ::: "memory");         \
                      __builtin_amdgcn_sched_barrier(0);                         \
                      __builtin_amdgcn_s_setprio(1); }
#define POST()      { __builtin_amdgcn_s_setprio(0); __builtin_amdgcn_s_barrier(); }
#define POST_V6()   { __builtin_amdgcn_s_setprio(0);                             \
                      asm volatile("s_waitcnt vmcnt(6)" ::: "memory");           \
                      __builtin_amdgcn_s_barrier(); }
#define POST_V0()   { __builtin_amdgcn_s_setprio(0);                             \
                      asm volatile("s_waitcnt vmcnt(0)" ::: "memory");           \
                      __builtin_amdgcn_s_barrier(); }

__global__ __launch_bounds__(512, 1) void gemm_i8_8phase(
        const signed char* __restrict__ A,      // [M][K] i8
        const signed char* __restrict__ W,      // [N][K] i8
        const float* __restrict__ qrow,         // [M] row dequant scale
        const float* __restrict__ scales,       // [N]
        const float* __restrict__ bias,         // [N]
        float* __restrict__ C,                  // [M][N]
        int M, int N, int K) {
    extern __shared__ signed char smem[];       // 131072 B

    const int tid  = threadIdx.x;
    const int wid  = tid >> 6;
    const int lane = tid & 63;
    const int wr = wid >> 2;     // 0..1
    const int wc = wid & 3;      // 0..3
    const int fr = lane & 15;
    const int fq = lane >> 4;

    const int nwg = gridDim.x;
    const int bid = blockIdx.x;
    const int swz = ((nwg & 7) == 0) ? ((bid & 7) * (nwg >> 3) + (bid >> 3)) : bid;
    const int tiles_n = N >> 8;
    const int tm = swz / tiles_n;
    const int tn = swz % tiles_n;
    const long arow = (long)tm * 256;
    const long brow = (long)tn * 256;

    i32x4 acc[8][4] = {};
    i32x4 fa[4][2], fb0[2][2], fb1[2][2];

    const int NT = K >> 7;       // K-tiles of 128; NT even, >= 4

#define STA(kt, h) stage_half(A, arow + (h) * 128, K, (kt) * 128, \
                              smem + ((kt) & 1) * 65536 + (h) * 16384, tid)
#define STB(kt, h) stage_half(W, brow + (h) * 128, K, (kt) * 128, \
                              smem + ((kt) & 1) * 65536 + 32768 + (h) * 16384, tid)

    // ---- prologue: 7 half-tile stages (tile0 full + tile1 minus A.h1)
    STA(0, 0); STB(0, 0); STA(0, 1); STB(0, 1);
    STA(1, 0); STB(1, 0); STB(1, 1);
    asm volatile("s_waitcnt vmcnt(6)" ::: "memory");   // tile0's 4 half-stages landed
    __builtin_amdgcn_s_barrier();

    // ---- main loop: iteration consumes tiles (2i)->buf0, (2i+1)->buf1
    for (int i = 0; i < (NT >> 1) - 1; ++i) {
        const int b = 2 * i + 1, c = 2 * i + 2, d = 2 * i + 3;
        // ph1 (mh0,nh0 of buf0)
        readA<0, 0>(smem, fa, wr, lane); readB<0, 0>(smem, fb0, wc, lane); STA(b, 1);
        SYNC_PRE(); mfmas<0, 0>(acc, fa, fb0); POST();
        // ph2 (mh0,nh1)
        readB<0, 1>(smem, fb1, wc, lane); STA(c, 0);
        SYNC_PRE(); mfmas<0, 1>(acc, fa, fb1); POST();
        // ph3 (mh1,nh0)
        readA<0, 1>(smem, fa, wr, lane); STB(c, 0);
        SYNC_PRE(); mfmas<1, 0>(acc, fa, fb0); POST();
        // ph4 (mh1,nh1) + fence: tile b fully landed before ph5 reads buf1
        STB(c, 1);
        SYNC_PRE(); mfmas<1, 1>(acc, fa, fb1); POST_V6();
        // ph5 (mh0,nh0 of buf1)
        readA<1, 0>(smem, fa, wr, lane); readB<1, 0>(smem, fb0, wc, lane); STA(c, 1);
        SYNC_PRE(); mfmas<0, 0>(acc, fa, fb0); POST();
        // ph6
        readB<1, 1>(smem, fb1, wc, lane); STA(d, 0);
        SYNC_PRE(); mfmas<0, 1>(acc, fa, fb1); POST();
        // ph7
        readA<1, 1>(smem, fa, wr, lane); STB(d, 0);
        SYNC_PRE(); mfmas<1, 0>(acc, fa, fb0); POST();
        // ph8 + fence: tile c fully landed before next-iter ph1 reads buf0
        STB(d, 1);
        SYNC_PRE(); mfmas<1, 1>(acc, fa, fb1); POST_V6();
    }

    // ---- epilogue iteration: tiles NT-2 (buf0), NT-1 (buf1); no further prefetch
    readA<0, 0>(smem, fa, wr, lane); readB<0, 0>(smem, fb0, wc, lane); STA(NT - 1, 1);
    SYNC_PRE(); mfmas<0, 0>(acc, fa, fb0); POST();
    readB<0, 1>(smem, fb1, wc, lane);
    SYNC_PRE(); mfmas<0, 1>(acc, fa, fb1); POST();
    readA<0, 1>(smem, fa, wr, lane);
    SYNC_PRE(); mfmas<1, 0>(acc, fa, fb0); POST();
    SYNC_PRE(); mfmas<1, 1>(acc, fa, fb1); POST_V0();   // drain: tile NT-1 fully landed
    readA<1, 0>(smem, fa, wr, lane); readB<1, 0>(smem, fb0, wc, lane);
    SYNC_PRE(); mfmas<0, 0>(acc, fa, fb0); POST();
    readB<1, 1>(smem, fb1, wc, lane);
    SYNC_PRE(); mfmas<0, 1>(acc, fa, fb1); POST();
    readA<1, 1>(smem, fa, wr, lane);
    SYNC_PRE(); mfmas<1, 0>(acc, fa, fb0); POST();
    SYNC_PRE(); mfmas<1, 1>(acc, fa, fb1);
    __builtin_amdgcn_s_setprio(0);

#undef STA
#undef STB

    // ---- dequant row scales: qr[m][j] for this thread's 32 output rows
    float qr[8][4];
#pragma unroll
    for (int mh = 0; mh < 2; ++mh)
#pragma unroll
        for (int ml = 0; ml < 4; ++ml) {
            const long row0 = arow + wr * 16 + mh * 128 + ml * 32 + fq * 4;
#pragma unroll
            for (int j = 0; j < 4; ++j)
                qr[mh * 4 + ml][j] = qrow[row0 + j];
        }

    // ---- C write: out = acc * qrow[row] * scales[col] + bias[col]
    // 16x16 C/D layout: col = lane&15, row = (lane>>4)*4 + reg
#pragma unroll
    for (int n = 0; n < 4; ++n) {
        const int col = tn * 256 + wc * 16 + n * 64 + fr;
        const float s = scales[col];
        const float bb = bias[col];
#pragma unroll
        for (int mh = 0; mh < 2; ++mh)
#pragma unroll
            for (int ml = 0; ml < 4; ++ml) {
                const int m = mh * 4 + ml;
                const long row0 = arow + wr * 16 + mh * 128 + ml * 32 + fq * 4;
#pragma unroll
                for (int j = 0; j < 4; ++j)
                    __builtin_nontemporal_store(
                        (float)acc[m][n][j] * (qr[m][j] * s) + bb,
                        &C[(row0 + j) * (long)N + col]);
            }
    }
}

// ---------------- fallback: plain fp32 (odd shapes / tiny ws only) ----------------
__global__ __launch_bounds__(256) void gemm_fallback_kernel(
        const float* __restrict__ A, const int* __restrict__ W,
        const float* __restrict__ scales, const float* __restrict__ bias,
        float* __restrict__ C, int M, int N, int K) {
    __shared__ float As[64][16];
    __shared__ float Ws[64][16];
    const int tiles_n = N / 64;
    const int tm = blockIdx.x / tiles_n, tn = blockIdx.x % tiles_n;
    const int tid = threadIdx.x, tx = tid & 15, ty = tid >> 4;
    float acc[4][4] = {};
    for (int k0 = 0; k0 < K; k0 += 16) {
        __syncthreads();
#pragma unroll
        for (int i = 0; i < 4; ++i) {
            const int idx = tid + i * 256;
            const int r = idx >> 4, c = idx & 15;
            As[r][c] = A[(long)(tm * 64 + r) * K + k0 + c];
            Ws[r][c] = (float)W[(long)(tn * 64 + r) * K + k0 + c];
        }
        __syncthreads();
#pragma unroll
        for (int kk = 0; kk < 16; ++kk) {
            float a[4], w[4];
#pragma unroll
            for (int r = 0; r < 4; ++r) a[r] = As[ty * 4 + r][kk];
#pragma unroll
            for (int c = 0; c < 4; ++c) w[c] = Ws[tx * 4 + c][kk];
#pragma unroll
            for (int r = 0; r < 4; ++r)
#pragma unroll
                for (int c = 0; c < 4; ++c) acc[r][c] += a[r] * w[c];
        }
    }
#pragma unroll
    for (int r = 0; r < 4; ++r)
#pragma unroll
        for (int c = 0; c < 4; ++c) {
            const int col = tn * 64 + tx * 4 + c;
            C[(long)(tm * 64 + ty * 4 + r) * N + col] = acc[r][c] * scales[col] + bias[col];
        }
}

extern "C" void kernel_launch(void* const* d_in, const int* in_sizes, int n_in,
                              void* d_out, int out_size, void* d_ws, size_t ws_size,
                              hipStream_t stream) {
    const float* A32    = (const float*)d_in[0];
    const int*   Wq     = (const int*)d_in[1];
    const float* scales = (const float*)d_in[2];
    const float* bias   = (const float*)d_in[3];
    float* C = (float*)d_out;

    const long aElems = in_sizes[0];        // M*K
    const long wElems = in_sizes[1];        // N*K
    const int  N = in_sizes[2];
    const int  K = (int)(wElems / N);
    const int  M = (int)(aElems / K);

    const size_t need = (size_t)aElems + (size_t)wElems + (size_t)M * 4 + 64;
    const bool div256 = (M % 256 == 0) && (N % 256 == 0) && (K % 256 == 0) && (K >= 512);

    if (ws_size >= need && div256) {
        signed char* Aq  = (signed char*)d_ws;
        signed char* Wq8 = Aq + aElems;
        float* qrow = (float*)(Wq8 + wElems);
        quant_rows_kernel<<<M, 256, 0, stream>>>(A32, Aq, qrow, K);
        cvt_i32_i8_kernel<<<2048, 256, 0, stream>>>(Wq, Wq8, wElems);
        const int nwg = (M / 256) * (N / 256);
        gemm_i8_8phase<<<nwg, 512, 131072, stream>>>(Aq, Wq8, qrow, scales, bias, C, M, N, K);
    } else {
        const int nwg = (M / 64) * (N / 64);
        gemm_fallback_kernel<<<nwg, 256, 0, stream>>>(A32, Wq, scales, bias, C, M, N, K);
    }
}